// Round 4
// baseline (338.447 us; speedup 1.0000x reference)
//
#include <hip/hip_runtime.h>

// out[b,s,k] = sum_n x[b,s,n] * W[k,n] + bias[k]
// W[k,n] = (W_q[k,n] - zeros[k,n/64]) * scales[k,n/64] * scale2[k] * mask[k,n]
// M = B*S = 8192 (rows of x), N = 4096 (reduction), K = 4096 (out features).

#define M_DIM 8192
#define N_DIM 4096
#define K_DIM 4096
#define BK 32
#define NT (N_DIM / BK)  // 128 K-tiles

typedef __bf16 bf16;
typedef __attribute__((ext_vector_type(8))) bf16 bf16x8;
typedef __attribute__((ext_vector_type(16))) float f32x16;

// ---------------------------------------------------------------- pre-pass 1
__global__ __launch_bounds__(256) void cvt_x_kernel(const float* __restrict__ x,
                                                    bf16* __restrict__ xb) {
  const long total = (long)M_DIM * N_DIM / 8;
  const long stride = (long)gridDim.x * blockDim.x;
  for (long t = (long)blockIdx.x * blockDim.x + threadIdx.x; t < total; t += stride) {
    const long e = t * 8;
    const float4 v0 = *reinterpret_cast<const float4*>(x + e);
    const float4 v1 = *reinterpret_cast<const float4*>(x + e + 4);
    bf16x8 o;
    o[0] = (bf16)v0.x; o[1] = (bf16)v0.y; o[2] = (bf16)v0.z; o[3] = (bf16)v0.w;
    o[4] = (bf16)v1.x; o[5] = (bf16)v1.y; o[6] = (bf16)v1.z; o[7] = (bf16)v1.w;
    *reinterpret_cast<bf16x8*>(xb + e) = o;
  }
}

// ---------------------------------------------------------------- pre-pass 2
__global__ __launch_bounds__(256) void deq_w_kernel(const int* __restrict__ Wq,
                                                    const float* __restrict__ scales,
                                                    const float* __restrict__ zeros,
                                                    const int* __restrict__ mask,
                                                    const float* __restrict__ scale2,
                                                    bf16* __restrict__ wb) {
  const int total = K_DIM * (N_DIM / 8);
  const int stride = gridDim.x * blockDim.x;
  for (int t = blockIdx.x * blockDim.x + threadIdx.x; t < total; t += stride) {
    const int k = t >> 9;
    const int n0 = (t & 511) << 3;
    const int g = n0 >> 6;
    const float s = scales[(k << 6) + g] * scale2[k];
    const float z = zeros[(k << 6) + g];
    const long base = (long)k * N_DIM + n0;
    const int4 q0 = *reinterpret_cast<const int4*>(Wq + base);
    const int4 q1 = *reinterpret_cast<const int4*>(Wq + base + 4);
    const int4 m0 = *reinterpret_cast<const int4*>(mask + base);
    const int4 m1 = *reinterpret_cast<const int4*>(mask + base + 4);
    bf16x8 o;
    o[0] = (bf16)(((float)q0.x - z) * s * (float)m0.x);
    o[1] = (bf16)(((float)q0.y - z) * s * (float)m0.y);
    o[2] = (bf16)(((float)q0.z - z) * s * (float)m0.z);
    o[3] = (bf16)(((float)q0.w - z) * s * (float)m0.w);
    o[4] = (bf16)(((float)q1.x - z) * s * (float)m1.x);
    o[5] = (bf16)(((float)q1.y - z) * s * (float)m1.y);
    o[6] = (bf16)(((float)q1.z - z) * s * (float)m1.z);
    o[7] = (bf16)(((float)q1.w - z) * s * (float)m1.w);
    *reinterpret_cast<bf16x8*>(wb + base) = o;
  }
}

// ---------------------------------------------------------------- GEMM
// Round-2 skeleton (proven: 0 bank conflicts, counted vmcnt(8), prefetch-3,
// ring-4 LDS, 1 barrier/K-step) with 32x32x16 MFMA (2382 vs 2075 TF pipe,
// half the MFMA issue slots).
//
// 256x256 tile, BK=32, 8 waves (2M x 4N), each wave owns 128x64 output as
// 4x2 fragments of 32x32. LDS ring of 4 K-tile slots (32 KB each: A 256x32
// + B 256x32 bf16), 128 KiB total.
//
// LDS region layout (T2 swizzle, measured 0 conflicts): logical (row, slot
// 0..3 of 8 bf16) at byte (row>>1)*128 + x*16, x = ((row&1)*4+slot)^((row>>1)&7).
// global_load_lds writes linearly -> per-lane GLOBAL source pre-permuted by
// the same involution (both-sides-or-neither).
__device__ inline void gload16(const bf16* g, bf16* l) {
  __builtin_amdgcn_global_load_lds(
      (const __attribute__((address_space(1))) void*)g,
      (__attribute__((address_space(3))) void*)l, 16, 0, 0);
}

__global__ __launch_bounds__(512, 2) void gemm_kernel(const bf16* __restrict__ xb,
                                                      const bf16* __restrict__ wb,
                                                      const float* __restrict__ bias,
                                                      float* __restrict__ out) {
  __shared__ bf16 lds[65536];  // 128 KiB: 4 slots x (8192 A + 8192 B) elements

  const int tid = threadIdx.x;
  const int lane = tid & 63;
  const int w = tid >> 6;
  const int wr = w >> 2;  // 0..1  (M half, 128 rows)
  const int wc = w & 3;   // 0..3  (N quarter, 64 cols)

  // T1: bijective XCD swizzle; nwg = 512, 512 % 8 == 0.
  const int gid = blockIdx.x;
  const int swz = ((gid & 7) << 6) | (gid >> 3);
  const int bm = swz & 31;  // 32 M-tiles; consecutive swz share bk (B panel in L2)
  const int bk = swz >> 5;  // 16 K-tiles
  const long m0 = (long)bm * 256;
  const long k0 = (long)bk * 256;

  // Staging source decode: linear region byte p -> logical (row, slot).
  const bf16 *srcA0, *srcA1, *srcB0, *srcB1;
  {
    const int p0 = w * 1024 + lane * 16;
    const int rp0 = p0 >> 7;
    const int v0 = ((p0 >> 4) & 7) ^ (rp0 & 7);
    const int row0 = rp0 * 2 + (v0 >> 2), col0 = (v0 & 3) * 8;
    const int p1 = 8192 + w * 1024 + lane * 16;
    const int rp1 = p1 >> 7;
    const int v1 = ((p1 >> 4) & 7) ^ (rp1 & 7);
    const int row1 = rp1 * 2 + (v1 >> 2), col1 = (v1 & 3) * 8;
    srcA0 = xb + (m0 + row0) * N_DIM + col0;
    srcA1 = xb + (m0 + row1) * N_DIM + col1;
    srcB0 = wb + (k0 + row0) * N_DIM + col0;
    srcB1 = wb + (k0 + row1) * N_DIM + col1;
  }

  // 32x32x16 fragment addressing. Lane l -> A row (l&31), k-half (l>>5).
  // Row = wr*128 + mb*32 + (l&31); slot = kk*2 + (l>>5).
  // Element offset = (row>>1)*64 + (x)*8, x = ((row&1)*4+slot)^((row>>1)&7).
  // mb*32 rows = 16 pairs ≡ 0 mod 8 -> x independent of mb; kk toggles bit 1.
  const int lp = (lane & 31) >> 1;  // row pair within 32-block
  const int x0 = (((lane & 1) << 2) | (lane >> 5)) ^ (lp & 7);
  const int aE = (wr * 64 + lp) * 64;          // + mb*1024 + (x0^(kk<<1))*8
  const int bE = 8192 + (wc * 32 + lp) * 64;   // + nb*1024 + (x0^(kk<<1))*8

  auto STAGE = [&](int t) {
    bf16* base = lds + (t & 3) * 16384;
    const int ko = t * BK;
    gload16(srcA0 + ko, base + w * 512);
    gload16(srcA1 + ko, base + 4096 + w * 512);
    gload16(srcB0 + ko, base + 8192 + w * 512);
    gload16(srcB1 + ko, base + 12288 + w * 512);
  };

  f32x16 acc[4][2] = {};

  // Prologue: 3 tiles in flight; vmcnt(8) => tile 0 landed (all waves after barrier).
  STAGE(0); STAGE(1); STAGE(2);
  asm volatile("s_waitcnt vmcnt(8)" ::: "memory");
  asm volatile("s_barrier" ::: "memory");

  for (int t = 0; t < NT; ++t) {
    const bf16* base = lds + (t & 3) * 16384;
    bf16x8 af[4][2], bfr[2][2];
#pragma unroll
    for (int mb = 0; mb < 4; ++mb)
#pragma unroll
      for (int kk = 0; kk < 2; ++kk)
        af[mb][kk] = *reinterpret_cast<const bf16x8*>(
            base + aE + mb * 1024 + (x0 ^ (kk << 1)) * 8);
#pragma unroll
    for (int nb = 0; nb < 2; ++nb)
#pragma unroll
      for (int kk = 0; kk < 2; ++kk)
        bfr[nb][kk] = *reinterpret_cast<const bf16x8*>(
            base + bE + nb * 1024 + (x0 ^ (kk << 1)) * 8);

    if (t + 3 < NT) STAGE(t + 3);  // targets slot (t-1)&3: reads drained < barrier(t-1)

    if (t < NT - 3)       asm volatile("s_waitcnt vmcnt(8)" ::: "memory");
    else if (t == NT - 3) asm volatile("s_waitcnt vmcnt(4)" ::: "memory");
    else                  asm volatile("s_waitcnt vmcnt(0)" ::: "memory");
    // lgkm drain pre-barrier: this iter's reads complete before the barrier,
    // so next iter's STAGE into this slot is WAR-safe with 1 barrier.
    asm volatile("s_waitcnt lgkmcnt(0)" ::: "memory");
    asm volatile("s_barrier" ::: "memory");
    __builtin_amdgcn_sched_barrier(0);

    __builtin_amdgcn_s_setprio(1);
#pragma unroll
    for (int kk = 0; kk < 2; ++kk)
#pragma unroll
      for (int mb = 0; mb < 4; ++mb)
#pragma unroll
        for (int nb = 0; nb < 2; ++nb)
          acc[mb][nb] = __builtin_amdgcn_mfma_f32_32x32x16_bf16(
              af[mb][kk], bfr[nb][kk], acc[mb][nb], 0, 0, 0);
    __builtin_amdgcn_s_setprio(0);
  }

  // Epilogue. 32x32 C/D layout (m74/m101): col = lane&31,
  // row = (reg&3) + 8*(reg>>2) + 4*(lane>>5).
  const int col0 = (int)k0 + wc * 64 + (lane & 31);
  const int rbase = (int)m0 + wr * 128 + 4 * (lane >> 5);
#pragma unroll
  for (int nb = 0; nb < 2; ++nb) {
    const float bv = bias[col0 + nb * 32];
#pragma unroll
    for (int mb = 0; mb < 4; ++mb) {
#pragma unroll
      for (int r = 0; r < 16; ++r) {
        const int row = rbase + mb * 32 + (r & 3) + 8 * (r >> 2);
        out[(long)row * K_DIM + col0 + nb * 32] = acc[mb][nb][r] + bv;
      }
    }
  }
}

// ---------------------------------------------------------------- launch
extern "C" void kernel_launch(void* const* d_in, const int* in_sizes, int n_in,
                              void* d_out, int out_size, void* d_ws, size_t ws_size,
                              hipStream_t stream) {
  const float* x      = (const float*)d_in[0];
  const int*   Wq     = (const int*)d_in[1];
  const float* scales = (const float*)d_in[2];
  const float* zeros  = (const float*)d_in[3];
  const int*   mask   = (const int*)d_in[4];
  const float* scale2 = (const float*)d_in[5];
  const float* bias   = (const float*)d_in[6];
  float* out = (float*)d_out;

  bf16* xb = (bf16*)d_ws;
  bf16* wb = (bf16*)((char*)d_ws + (size_t)M_DIM * N_DIM * 2);

  cvt_x_kernel<<<2048, 256, 0, stream>>>(x, xb);
  deq_w_kernel<<<2048, 256, 0, stream>>>(Wq, scales, zeros, mask, scale2, wb);

  // Grid: (M/256) * (K/256) = 32 * 16 = 512 blocks, 512 threads.
  gemm_kernel<<<512, 512, 0, stream>>>(xb, wb, bias, out);
}

// Round 5
// 303.077 us; speedup vs baseline: 1.1167x; 1.1167x over previous
//
#include <hip/hip_runtime.h>

// out[b,s,k] = sum_n x[b,s,n] * W[k,n] + bias[k]
// W[k,n] = (W_q[k,n] - zeros[k,n/64]) * scales[k,n/64] * scale2[k] * mask[k,n]
// M = B*S = 8192 (rows of x), N = 4096 (reduction), K = 4096 (out features).

#define M_DIM 8192
#define N_DIM 4096
#define K_DIM 4096
#define NT 64  // K-tiles of BK=64

typedef __bf16 bf16;
typedef __attribute__((ext_vector_type(8))) bf16 bf16x8;
typedef __attribute__((ext_vector_type(4))) float f32x4;

// ---------------------------------------------------------------- pre-pass 1
__global__ __launch_bounds__(256) void cvt_x_kernel(const float* __restrict__ x,
                                                    bf16* __restrict__ xb) {
  const long total = (long)M_DIM * N_DIM / 8;
  const long stride = (long)gridDim.x * blockDim.x;
  for (long t = (long)blockIdx.x * blockDim.x + threadIdx.x; t < total; t += stride) {
    const long e = t * 8;
    const float4 v0 = *reinterpret_cast<const float4*>(x + e);
    const float4 v1 = *reinterpret_cast<const float4*>(x + e + 4);
    bf16x8 o;
    o[0] = (bf16)v0.x; o[1] = (bf16)v0.y; o[2] = (bf16)v0.z; o[3] = (bf16)v0.w;
    o[4] = (bf16)v1.x; o[5] = (bf16)v1.y; o[6] = (bf16)v1.z; o[7] = (bf16)v1.w;
    *reinterpret_cast<bf16x8*>(xb + e) = o;
  }
}

// ---------------------------------------------------------------- pre-pass 2
__global__ __launch_bounds__(256) void deq_w_kernel(const int* __restrict__ Wq,
                                                    const float* __restrict__ scales,
                                                    const float* __restrict__ zeros,
                                                    const int* __restrict__ mask,
                                                    const float* __restrict__ scale2,
                                                    bf16* __restrict__ wb) {
  const int total = K_DIM * (N_DIM / 8);
  const int stride = gridDim.x * blockDim.x;
  for (int t = blockIdx.x * blockDim.x + threadIdx.x; t < total; t += stride) {
    const int k = t >> 9;
    const int n0 = (t & 511) << 3;
    const int g = n0 >> 6;
    const float s = scales[(k << 6) + g] * scale2[k];
    const float z = zeros[(k << 6) + g];
    const long base = (long)k * N_DIM + n0;
    const int4 q0 = *reinterpret_cast<const int4*>(Wq + base);
    const int4 q1 = *reinterpret_cast<const int4*>(Wq + base + 4);
    const int4 m0 = *reinterpret_cast<const int4*>(mask + base);
    const int4 m1 = *reinterpret_cast<const int4*>(mask + base + 4);
    bf16x8 o;
    o[0] = (bf16)(((float)q0.x - z) * s * (float)m0.x);
    o[1] = (bf16)(((float)q0.y - z) * s * (float)m0.y);
    o[2] = (bf16)(((float)q0.z - z) * s * (float)m0.z);
    o[3] = (bf16)(((float)q0.w - z) * s * (float)m0.w);
    o[4] = (bf16)(((float)q1.x - z) * s * (float)m1.x);
    o[5] = (bf16)(((float)q1.y - z) * s * (float)m1.y);
    o[6] = (bf16)(((float)q1.z - z) * s * (float)m1.z);
    o[7] = (bf16)(((float)q1.w - z) * s * (float)m1.w);
    *reinterpret_cast<bf16x8*>(wb + base) = o;
  }
}

// ---------------------------------------------------------------- GEMM
// 256x256 tile, BK=64, 8 waves (2M x 4N), 16x16x32 MFMA, 4-phase-per-K-tile
// schedule (8 phases / 2 K-tiles), double-buffered LDS (128 KiB), one counted
// vmcnt(6) per K-tile (never 0 in main loop).
//
// LDS per buffer (32768 elem): A region [0,16384) = 256 rows x 64 cols bf16,
// B region [16384,32768). Row = 128 B; swizzle: (row, slot 0..7 of 8 bf16)
// at byte row*128 + x*16, x = slot ^ (row&7). global_load_lds writes linearly
// -> per-lane GLOBAL source pre-permuted by the same involution.
//
// Half-tiles (16 KB each, 2 gload/thread) are quadrant-row unions so each is
// read in exactly ONE phase:
//   A-half h = rows {wr*128 + [h*64, h*64+64)}  (all waves' mh=h rows)
//   B-half h = rows {wc*64  + [h*32, h*32+32)}  (all waves' nh=h rows)
// Phase reads: ph0: Ah0+Bh0; ph1: Bh1; ph2: Ah1; ph3: none (regs held).
// Stages:      ph0: Ah1(t+1)->other buf; ph1: Ah0(t+2)->cur (dead since ph0);
//              ph2: Bh0(t+2)->cur (dead since ph0); ph3: Bh1(t+2)->cur (dead
//              since ph1). FIFO deadline-monotone; vmcnt(6) at ph3 retires
//              exactly through Ah1(t+1) => tile t+1 fully landed.
__device__ inline void gload16(const bf16* g, bf16* l) {
  __builtin_amdgcn_global_load_lds(
      (const __attribute__((address_space(1))) void*)g,
      (__attribute__((address_space(3))) void*)l, 16, 0, 0);
}

#define BARRIER asm volatile("s_barrier" ::: "memory")
#define LGKM0   asm volatile("s_waitcnt lgkmcnt(0)" ::: "memory")
#define VM6     asm volatile("s_waitcnt vmcnt(6)" ::: "memory")
#define VM0     asm volatile("s_waitcnt vmcnt(0)" ::: "memory")
#define SBAR    __builtin_amdgcn_sched_barrier(0)

__global__ __launch_bounds__(512, 2) void gemm_kernel(const bf16* __restrict__ xb,
                                                      const bf16* __restrict__ wb,
                                                      const float* __restrict__ bias,
                                                      float* __restrict__ out) {
  __shared__ bf16 lds[65536];  // 128 KiB: 2 buffers x (16K A + 16K B) elements

  const int tid = threadIdx.x;
  const int lane = tid & 63;
  const int w = tid >> 6;
  const int wr = w >> 2;  // 0..1  (M half, 128 rows)
  const int wc = w & 3;   // 0..3  (N quarter, 64 cols)

  // T1: bijective XCD swizzle; nwg = 512 % 8 == 0.
  const int gid = blockIdx.x;
  const int swz = ((gid & 7) << 6) | (gid >> 3);
  const int bm = swz & 31;  // 32 M-tiles
  const int bk = swz >> 5;  // 16 K-tiles
  const long m0 = (long)bm * 256;
  const long k0 = (long)bk * 256;

  // ---- staging source decode (inverse swizzle), per-thread constants.
  // A: thread t covers region bytes t*16 within each 8 KB row-band.
  const int browA = tid >> 3;                      // 0..63
  const int slotA = (tid & 7) ^ (browA & 7);
  const bf16* baseA = xb + (m0 + browA) * N_DIM + slotA * 8;
  // B: u = t&255 within band; wcb = t>>8 selects band pair.
  const int u = tid & 255;
  const int wcb = tid >> 8;                        // 0..1
  const int browB = u >> 3;                        // 0..31
  const int slotB = (u & 7) ^ (browB & 7);
  const bf16* baseB = wb + (k0 + wcb * 64 + browB) * N_DIM + slotB * 8;

  // ---- ds_read fragment bases. Lane: row += (lane&15); k-slot = kk*4+(lane>>4);
  // x = (kk*4 + (lane>>4)) ^ (lane&7)  [row&7 == lane&7 for all frag rows].
  const int ln15 = lane & 15;
  const int x0 = (lane >> 4) ^ (lane & 7);
  int aoffk[2], boffk[2];
#pragma unroll
  for (int kk = 0; kk < 2; ++kk) {
    const int x = x0 ^ (kk << 2);
    aoffk[kk] = (wr * 128 + ln15) * 64 + x * 8;
    boffk[kk] = 16384 + (wc * 64 + ln15) * 64 + x * 8;
  }

  f32x4 acc[8][4] = {};
  bf16x8 af[4][2], bfA[2][2], bfB[2][2];

  auto STA = [&](int tt, int bsel, int h) {  // stage A-half h of tile tt
    const bf16* s = baseA + (long)(h * 64) * N_DIM + tt * 64;
    bf16* d = lds + bsel * 32768 + h * 4096 + (tid << 3);
    gload16(s, d);                            // rows [h*64, +64)
    gload16(s + (long)128 * N_DIM, d + 8192); // rows [128+h*64, +64)
  };
  auto STB = [&](int tt, int bsel, int h) {  // stage B-half h of tile tt
    const bf16* s = baseB + (long)(h * 32) * N_DIM + tt * 64;
    bf16* d = lds + bsel * 32768 + 16384 + wcb * 4096 + h * 2048 + (u << 3);
    gload16(s, d);                            // wc bands {wcb}
    gload16(s + (long)128 * N_DIM, d + 8192); // wc bands {wcb+2}
  };
  auto LDA = [&](int cb, int mh) {
#pragma unroll
    for (int mf = 0; mf < 4; ++mf)
#pragma unroll
      for (int kk = 0; kk < 2; ++kk)
        af[mf][kk] = *reinterpret_cast<const bf16x8*>(
            lds + cb + aoffk[kk] + mh * 4096 + mf * 1024);
  };
  auto LDB = [&](bf16x8 (*bf)[2], int cb, int nh) {
#pragma unroll
    for (int nf = 0; nf < 2; ++nf)
#pragma unroll
      for (int kk = 0; kk < 2; ++kk)
        bf[nf][kk] = *reinterpret_cast<const bf16x8*>(
            lds + cb + boffk[kk] + nh * 2048 + nf * 1024);
  };
  auto MFMA_Q = [&](bf16x8 (*bf)[2], int mh, int nh) {
    __builtin_amdgcn_s_setprio(1);
#pragma unroll
    for (int kk = 0; kk < 2; ++kk)
#pragma unroll
      for (int mf = 0; mf < 4; ++mf)
#pragma unroll
        for (int nf = 0; nf < 2; ++nf)
          acc[mh * 4 + mf][nh * 2 + nf] = __builtin_amdgcn_mfma_f32_16x16x32_bf16(
              af[mf][kk], bf[nf][kk], acc[mh * 4 + mf][nh * 2 + nf], 0, 0, 0);
    __builtin_amdgcn_s_setprio(0);
  };

  // Prologue (FIFO order = consumption order): tile0 {Ah0,Bh0,Bh1,Ah1},
  // tile1 {Ah0,Bh0,Bh1}. 14 loads; vmcnt(6) retires tile0's 8.
  STA(0, 0, 0); STB(0, 0, 0); STB(0, 0, 1); STA(0, 0, 1);
  STA(1, 1, 0); STB(1, 1, 0); STB(1, 1, 1);
  VM6; BARRIER;

  auto TILE = [&](int t, int c) {
    const int cb = c * 32768;
    // ph0: read Ah0 + Bh0; stage Ah1(t+1) -> other buf
    LDA(cb, 0); LDB(bfA, cb, 0);
    if (t + 1 < NT) STA(t + 1, c ^ 1, 1);
    asm volatile("s_waitcnt lgkmcnt(8)" ::: "memory");
    BARRIER; LGKM0; SBAR;
    MFMA_Q(bfA, 0, 0); SBAR; BARRIER;
    // ph1: read Bh1; stage Ah0(t+2) -> cur buf (region dead since ph0)
    LDB(bfB, cb, 1);
    if (t + 2 < NT) STA(t + 2, c, 0);
    BARRIER; LGKM0; SBAR;
    MFMA_Q(bfB, 0, 1); SBAR; BARRIER;
    // ph2: read Ah1 (reuse af regs); stage Bh0(t+2) -> cur (dead since ph0)
    LDA(cb, 1);
    if (t + 2 < NT) STB(t + 2, c, 0);
    BARRIER; LGKM0; SBAR;
    MFMA_Q(bfA, 1, 0); SBAR; BARRIER;
    // ph3: no reads; stage Bh1(t+2) -> cur (dead since ph1); counted wait
    if (t + 2 < NT) STB(t + 2, c, 1);
    if (t < NT - 2) { VM6; } else { VM0; }
    BARRIER; LGKM0; SBAR;
    MFMA_Q(bfB, 1, 1); SBAR; BARRIER;
  };

  for (int tp = 0; tp < NT / 2; ++tp) {
    TILE(2 * tp, 0);
    TILE(2 * tp + 1, 1);
  }

  // Epilogue. C/D: col = lane&15 (K-dim), row = (lane>>4)*4 + r (M-dim).
  const int ocol0 = (int)k0 + wc * 64 + ln15;
  const int orow0 = (int)m0 + wr * 128 + (lane >> 4) * 4;
#pragma unroll
  for (int ni = 0; ni < 4; ++ni) {
    const float bv = bias[ocol0 + ni * 16];
#pragma unroll
    for (int mi = 0; mi < 8; ++mi)
#pragma unroll
      for (int r = 0; r < 4; ++r)
        out[(long)(orow0 + mi * 16 + r) * K_DIM + ocol0 + ni * 16] =
            acc[mi][ni][r] + bv;
  }
}

// ---------------------------------------------------------------- launch
extern "C" void kernel_launch(void* const* d_in, const int* in_sizes, int n_in,
                              void* d_out, int out_size, void* d_ws, size_t ws_size,
                              hipStream_t stream) {
  const float* x      = (const float*)d_in[0];
  const int*   Wq     = (const int*)d_in[1];
  const float* scales = (const float*)d_in[2];
  const float* zeros  = (const float*)d_in[3];
  const int*   mask   = (const int*)d_in[4];
  const float* scale2 = (const float*)d_in[5];
  const float* bias   = (const float*)d_in[6];
  float* out = (float*)d_out;

  bf16* xb = (bf16*)d_ws;
  bf16* wb = (bf16*)((char*)d_ws + (size_t)M_DIM * N_DIM * 2);

  cvt_x_kernel<<<2048, 256, 0, stream>>>(x, xb);
  deq_w_kernel<<<2048, 256, 0, stream>>>(Wq, scales, zeros, mask, scale2, wb);

  // Grid: (M/256) * (K/256) = 32 * 16 = 512 blocks, 512 threads.
  gemm_kernel<<<512, 512, 0, stream>>>(xb, wb, bias, out);
}